// Round 5
// baseline (465.330 us; speedup 1.0000x reference)
//
#include <hip/hip_runtime.h>
#include <hip/hip_bf16.h>
#include <math.h>

typedef __attribute__((ext_vector_type(8))) short short8v;
typedef __attribute__((ext_vector_type(4))) unsigned short ushort4v;
typedef __attribute__((ext_vector_type(8))) unsigned short ushort8v;
typedef __attribute__((ext_vector_type(4))) unsigned uint4v;
typedef __attribute__((ext_vector_type(4))) float f32x4;

__device__ inline unsigned short f2bf(float f) {  // RNE
    unsigned u = __float_as_uint(f);
    return (unsigned short)((u + 0x7fffu + ((u >> 16) & 1u)) >> 16);
}
__device__ inline float bflo(unsigned u) { return __uint_as_float(u << 16); }
__device__ inline float bfhi(unsigned u) { return __uint_as_float(u & 0xffff0000u); }
__device__ inline float bf1(unsigned short s) { return __uint_as_float((unsigned)s << 16); }
__device__ inline unsigned pk2(float a, float b) {  // packed f32x2 -> bf16x2 (RNE)
    __hip_bfloat162 h = __float22bfloat162_rn(make_float2(a, b));
    unsigned r;
    __builtin_memcpy(&r, &h, 4);
    return r;
}

// ---------------------------------------------------------------------------
// CSR build
// ---------------------------------------------------------------------------
__global__ void k_deg(const int* __restrict__ dst, int* __restrict__ deg, int E) {
    int e = blockIdx.x * blockDim.x + threadIdx.x;
    if (e < E) atomicAdd(&deg[dst[e]], 1);
}

__global__ void k_dinv(const int* __restrict__ deg, float* __restrict__ dinv, int N) {
    int i = blockIdx.x * blockDim.x + threadIdx.x;
    if (i < N) dinv[i] = rsqrtf((float)(deg[i] + 1));  // +1 self loop
}

// --- hierarchical exclusive scan: 1024-elem tiles ---------------------------
__global__ __launch_bounds__(256) void k_bsum(const int* __restrict__ deg,
                                              int* __restrict__ bsum, int n) {
    __shared__ int r[256];
    int b = blockIdx.x, tid = threadIdx.x;
    int i0 = b * 1024 + tid * 4;
    int s = 0;
#pragma unroll
    for (int j = 0; j < 4; ++j)
        if (i0 + j < n) s += deg[i0 + j];
    r[tid] = s;
    __syncthreads();
    for (int off = 128; off > 0; off >>= 1) {
        if (tid < off) r[tid] += r[tid + off];
        __syncthreads();
    }
    if (tid == 0) bsum[b] = r[0];
}

__global__ __launch_bounds__(1024) void k_scan2(const int* __restrict__ bsum,
                                                int* __restrict__ bpre,
                                                int* __restrict__ total_out, int nb) {
    __shared__ int ls[1024];
    int tid = threadIdx.x;
    int v = (tid < nb) ? bsum[tid] : 0;
    ls[tid] = v;
    __syncthreads();
    for (int off = 1; off < 1024; off <<= 1) {
        int t = (tid >= off) ? ls[tid - off] : 0;
        __syncthreads();
        ls[tid] += t;
        __syncthreads();
    }
    if (tid < nb) bpre[tid] = ls[tid] - v;
    if (tid == 1023) *total_out = ls[1023];
}

__global__ __launch_bounds__(256) void k_scan3(const int* __restrict__ deg,
                                               const int* __restrict__ bpre,
                                               int* __restrict__ offsets, int n) {
    __shared__ int ts[256];
    int b = blockIdx.x, tid = threadIdx.x;
    int i0 = b * 1024 + tid * 4;
    int v[4] = {0, 0, 0, 0};
#pragma unroll
    for (int j = 0; j < 4; ++j)
        if (i0 + j < n) v[j] = deg[i0 + j];
    int s = v[0] + v[1] + v[2] + v[3];
    ts[tid] = s;
    __syncthreads();
    for (int off = 1; off < 256; off <<= 1) {
        int t = (tid >= off) ? ts[tid - off] : 0;
        __syncthreads();
        ts[tid] += t;
        __syncthreads();
    }
    int excl = bpre[b] + ts[tid] - s;
#pragma unroll
    for (int j = 0; j < 4; ++j) {
        if (i0 + j < n) offsets[i0 + j] = excl;
        excl += v[j];
    }
}

__global__ void k_fill(const int* __restrict__ src, const int* __restrict__ dst,
                       const int* __restrict__ offsets, int* __restrict__ cursor,
                       int* __restrict__ esrc, int E) {
    int e = blockIdx.x * blockDim.x + threadIdx.x;
    if (e < E) {
        int d = dst[e];
        int p = offsets[d] + atomicAdd(&cursor[d], 1);
        esrc[p] = src[e];
    }
}

// ---------------------------------------------------------------------------
// W1 -> bf16, pre-swizzled into per-lane MFMA B-fragment order.
// ---------------------------------------------------------------------------
__global__ void k_wswz(const float* __restrict__ W1, unsigned short* __restrict__ Wswz) {
    int t = blockIdx.x * blockDim.x + threadIdx.x;
    if (t >= 16 * 8 * 64) return;
    int l = t & 63, cb = (t >> 6) & 7, ks = t >> 9;
    int col = cb * 16 + (l & 15);
    int kb = ks * 32 + 8 * (l >> 4);
    ushort8v w;
#pragma unroll
    for (int j = 0; j < 8; ++j) w[j] = f2bf(W1[(size_t)(kb + j) * 128 + col]);
    *(ushort8v*)(Wswz + (size_t)t * 8) = w;
}

// ---------------------------------------------------------------------------
// GEMM1: h0s[M,128](bf16) = dinv[i] * (x[i,:] @ W1).
// 128x128 tile, 4 waves 2x2. A-fragments loaded DIRECTLY from x (no LDS
// staging, no K-loop barriers): block's 128x128B K-window fits L1, so the
// (g, wc) 4x reuse is cache-absorbed. Packed f32->bf16 cvt in registers.
// ---------------------------------------------------------------------------
#define CP 132  // epilogue transpose pitch (shorts)

__global__ __launch_bounds__(256) void k_gemm1(const float* __restrict__ x,
                                               const unsigned short* __restrict__ Wswz,
                                               const float* __restrict__ dinv,
                                               unsigned short* __restrict__ h0s, int M) {
    __shared__ unsigned short lds[128 * CP];  // epilogue only
    int tid = threadIdx.x;
    int wid = tid >> 6, lane = tid & 63;
    int wr = wid >> 1, wc = wid & 1;
    int g = lane >> 4, lr = lane & 15;
    int brow = blockIdx.x * 128;

    f32x4 acc[4][4];
#pragma unroll
    for (int m = 0; m < 4; ++m)
#pragma unroll
        for (int n = 0; n < 4; ++n) acc[m][n] = (f32x4){0.f, 0.f, 0.f, 0.f};

    for (int k0 = 0; k0 < 512; k0 += 32) {
        int ks = k0 >> 5;
        short8v bfr[4];
#pragma unroll
        for (int n = 0; n < 4; ++n) {
            int cb = wc * 4 + n;
            bfr[n] = *(const short8v*)(Wswz + (size_t)((ks * 8 + cb) * 64 + lane) * 8);
        }
        short8v afr[4];
#pragma unroll
        for (int m = 0; m < 4; ++m) {
            int gr = brow + wr * 64 + m * 16 + lr;
            float4 lo = make_float4(0.f, 0.f, 0.f, 0.f);
            float4 hi = make_float4(0.f, 0.f, 0.f, 0.f);
            if (gr < M) {
                const float* ap = x + (size_t)gr * 512 + k0 + g * 8;
                lo = *(const float4*)ap;
                hi = *(const float4*)(ap + 4);
            }
            union { uint4v u; short8v s; } cv;
            cv.u[0] = pk2(lo.x, lo.y);
            cv.u[1] = pk2(lo.z, lo.w);
            cv.u[2] = pk2(hi.x, hi.y);
            cv.u[3] = pk2(hi.z, hi.w);
            afr[m] = cv.s;
        }
#pragma unroll
        for (int m = 0; m < 4; ++m)
#pragma unroll
            for (int n = 0; n < 4; ++n)
                acc[m][n] = __builtin_amdgcn_mfma_f32_16x16x32_bf16(afr[m], bfr[n],
                                                                    acc[m][n], 0, 0, 0);
    }
    // C/D: col = l&15, row = 4*(l>>4)+reg ; scale by dinv[row], bf16-stage in LDS
#pragma unroll
    for (int m = 0; m < 4; ++m) {
        int row0 = wr * 64 + m * 16 + g * 4;
        float dv[4];
#pragma unroll
        for (int r = 0; r < 4; ++r) {
            int gr = brow + row0 + r;
            dv[r] = (gr < M) ? dinv[gr] : 0.f;
        }
#pragma unroll
        for (int n = 0; n < 4; ++n) {
            int col = wc * 64 + n * 16 + lr;
#pragma unroll
            for (int r = 0; r < 4; ++r)
                lds[(row0 + r) * CP + col] = f2bf(acc[m][n][r] * dv[r]);
        }
    }
    __syncthreads();
    {
        int row = tid >> 1, half = tid & 1;
        int gr = brow + row;
        if (gr < M) {
            unsigned short* dst = h0s + (size_t)gr * 128 + half * 64;
            const unsigned short* src = &lds[row * CP + half * 64];
#pragma unroll
            for (int i = 0; i < 16; ++i)
                *(ushort4v*)(dst + i * 4) = *(const ushort4v*)(src + i * 4);
        }
    }
}

// ---------------------------------------------------------------------------
// Aggregation 1: h1[i] = relu( dinv[i] * (h0s[i] + sum_e h0s[src]) + b1 )
// One wave per node; coalesced index prefetch + shfl broadcast; 8x unrolled.
// ---------------------------------------------------------------------------
__global__ __launch_bounds__(256) void k_agg1(const unsigned short* __restrict__ h0s,
                                              const float* __restrict__ dinv,
                                              const int* __restrict__ offsets,
                                              const int* __restrict__ esrc,
                                              const float* __restrict__ b1,
                                              float* __restrict__ h1, int N) {
    int wid = (blockIdx.x * 256 + threadIdx.x) >> 6;
    if (wid >= N) return;
    int lane = threadIdx.x & 63;
    const unsigned* base = (const unsigned*)h0s;  // row i = base + i*64
    unsigned us = base[(size_t)wid * 64 + lane];
    float ax = bflo(us), ay = bfhi(us);           // self term (prescaled)
    int beg = offsets[wid], end = offsets[wid + 1];
    for (int b0 = beg; b0 < end; b0 += 64) {
        int nb = min(64, end - b0);
        int idx = (lane < nb) ? esrc[b0 + lane] : 0;
        int k = 0;
        for (; k + 8 <= nb; k += 8) {
            unsigned v[8];
#pragma unroll
            for (int j = 0; j < 8; ++j) {
                int s = __shfl(idx, k + j);
                v[j] = base[(size_t)s * 64 + lane];
            }
#pragma unroll
            for (int j = 0; j < 8; ++j) {
                ax += bflo(v[j]);
                ay += bfhi(v[j]);
            }
        }
        for (; k + 4 <= nb; k += 4) {
            int s0 = __shfl(idx, k + 0), s1 = __shfl(idx, k + 1);
            int s2 = __shfl(idx, k + 2), s3 = __shfl(idx, k + 3);
            unsigned v0 = base[(size_t)s0 * 64 + lane];
            unsigned v1 = base[(size_t)s1 * 64 + lane];
            unsigned v2 = base[(size_t)s2 * 64 + lane];
            unsigned v3 = base[(size_t)s3 * 64 + lane];
            ax += (bflo(v0) + bflo(v1)) + (bflo(v2) + bflo(v3));
            ay += (bfhi(v0) + bfhi(v1)) + (bfhi(v2) + bfhi(v3));
        }
        for (; k < nb; ++k) {
            int s = __shfl(idx, k);
            unsigned v = base[(size_t)s * 64 + lane];
            ax += bflo(v);
            ay += bfhi(v);
        }
    }
    float di = dinv[wid];
    float2 bb = ((const float2*)b1)[lane];
    ((float2*)(h1 + (size_t)wid * 128))[lane] =
        make_float2(fmaxf(fmaf(di, ax, bb.x), 0.f), fmaxf(fmaf(di, ay, bb.y), 0.f));
}

// ---------------------------------------------------------------------------
// GEMM2: h2s[M,40](bf16) = dinv[r] * (h1[r,:] @ W2). Row per thread, W2 in LDS.
// ---------------------------------------------------------------------------
__global__ __launch_bounds__(256) void k_gemm2(const float* __restrict__ h1,
                                               const float* __restrict__ W2,
                                               const float* __restrict__ dinv,
                                               unsigned short* __restrict__ h2s, int N) {
    __shared__ float w2s[128 * 40];
    int tid = threadIdx.x;
    for (int i = tid; i < 128 * 40; i += 256) w2s[i] = W2[i];
    __syncthreads();
    int r = blockIdx.x * 256 + tid;
    if (r >= N) return;
    const float4* row = (const float4*)(h1 + (size_t)r * 128);
    float acc[40];
#pragma unroll
    for (int c = 0; c < 40; ++c) acc[c] = 0.f;
    for (int k4 = 0; k4 < 32; ++k4) {
        float4 a = row[k4];
        float aa[4] = {a.x, a.y, a.z, a.w};
        int kb = k4 * 4;
#pragma unroll
        for (int kk = 0; kk < 4; ++kk) {
            float av = aa[kk];
            const float4* wr = (const float4*)&w2s[(kb + kk) * 40];
#pragma unroll
            for (int c4 = 0; c4 < 10; ++c4) {
                float4 w = wr[c4];
                acc[c4 * 4 + 0] = fmaf(av, w.x, acc[c4 * 4 + 0]);
                acc[c4 * 4 + 1] = fmaf(av, w.y, acc[c4 * 4 + 1]);
                acc[c4 * 4 + 2] = fmaf(av, w.z, acc[c4 * 4 + 2]);
                acc[c4 * 4 + 3] = fmaf(av, w.w, acc[c4 * 4 + 3]);
            }
        }
    }
    float di = dinv[r];
    unsigned short* op = h2s + (size_t)r * 40;
#pragma unroll
    for (int c4 = 0; c4 < 10; ++c4) {
        ushort4v w;
        w[0] = f2bf(acc[c4 * 4 + 0] * di); w[1] = f2bf(acc[c4 * 4 + 1] * di);
        w[2] = f2bf(acc[c4 * 4 + 2] * di); w[3] = f2bf(acc[c4 * 4 + 3] * di);
        *(ushort4v*)(op + c4 * 4) = w;
    }
}

// ---------------------------------------------------------------------------
// Aggregation 2 + bias + log_softmax.
// ---------------------------------------------------------------------------
__global__ __launch_bounds__(256) void k_agg2(const unsigned short* __restrict__ h2s,
                                              const float* __restrict__ dinv,
                                              const int* __restrict__ offsets,
                                              const int* __restrict__ esrc,
                                              const float* __restrict__ b2,
                                              float* __restrict__ out, int N) {
    int wid = (blockIdx.x * 256 + threadIdx.x) >> 6;
    if (wid >= N) return;
    int lane = threadIdx.x & 63;
    bool act = lane < 40;
    float acc = act ? bf1(h2s[(size_t)wid * 40 + lane]) : 0.f;  // self (prescaled)
    int beg = offsets[wid], end = offsets[wid + 1];
    for (int b0 = beg; b0 < end; b0 += 64) {
        int nb = min(64, end - b0);
        int idx = (lane < nb) ? esrc[b0 + lane] : 0;
        int k = 0;
        for (; k + 8 <= nb; k += 8) {
            float u[8];
#pragma unroll
            for (int j = 0; j < 8; ++j) {
                int s = __shfl(idx, k + j);
                u[j] = act ? bf1(h2s[(size_t)s * 40 + lane]) : 0.f;
            }
            acc += ((u[0] + u[1]) + (u[2] + u[3])) + ((u[4] + u[5]) + (u[6] + u[7]));
        }
        for (; k + 4 <= nb; k += 4) {
            int s0 = __shfl(idx, k + 0), s1 = __shfl(idx, k + 1);
            int s2 = __shfl(idx, k + 2), s3 = __shfl(idx, k + 3);
            float u0 = act ? bf1(h2s[(size_t)s0 * 40 + lane]) : 0.f;
            float u1 = act ? bf1(h2s[(size_t)s1 * 40 + lane]) : 0.f;
            float u2 = act ? bf1(h2s[(size_t)s2 * 40 + lane]) : 0.f;
            float u3 = act ? bf1(h2s[(size_t)s3 * 40 + lane]) : 0.f;
            acc += (u0 + u1) + (u2 + u3);
        }
        for (; k < nb; ++k) {
            int s = __shfl(idx, k);
            acc += act ? bf1(h2s[(size_t)s * 40 + lane]) : 0.f;
        }
    }
    float di = dinv[wid];
    float logit = fmaf(di, acc, act ? b2[lane] : 0.f);
    float m = act ? logit : -1e30f;
#pragma unroll
    for (int o = 32; o > 0; o >>= 1) m = fmaxf(m, __shfl_xor(m, o));
    float pv = act ? __expf(logit - m) : 0.f;
    float ssum = pv;
#pragma unroll
    for (int o = 32; o > 0; o >>= 1) ssum += __shfl_xor(ssum, o);
    if (act) out[(size_t)wid * 40 + lane] = logit - m - __logf(ssum);
}

extern "C" void kernel_launch(void* const* d_in, const int* in_sizes, int n_in,
                              void* d_out, int out_size, void* d_ws, size_t ws_size,
                              hipStream_t stream) {
    const float* x  = (const float*)d_in[0];
    const int*   ei = (const int*)d_in[1];
    const float* W1 = (const float*)d_in[2];
    const float* b1 = (const float*)d_in[3];
    const float* W2 = (const float*)d_in[4];
    const float* b2 = (const float*)d_in[5];
    float* out = (float*)d_out;

    int N = in_sizes[0] / 512;
    int E = in_sizes[1] / 2;
    const int* esrc_in = ei;
    const int* edst_in = ei + E;
    int nb = (N + 1023) / 1024;  // scan tiles

    char* p = (char*)d_ws;
    size_t off = 0;
    auto take = [&](size_t bytes) {
        size_t o = (off + 255) & ~(size_t)255;
        off = o + bytes;
        return (void*)(p + o);
    };
    unsigned short* h0s  = (unsigned short*)take((size_t)N * 128 * 2);  // bf16 prescaled
    float*          h1   = (float*)take((size_t)N * 128 * 4);
    unsigned short* wswz = (unsigned short*)take((size_t)16 * 8 * 64 * 8 * 2);
    int*   deg  = (int*)take((size_t)N * 4);
    float* dinv = (float*)take((size_t)N * 4);
    int*   offs = (int*)take((size_t)(N + 1) * 4);
    int*   cur  = (int*)take((size_t)N * 4);
    int*   bsum = (int*)take((size_t)nb * 4);
    int*   bpre = (int*)take((size_t)nb * 4);
    int*   esrc = (int*)take((size_t)E * 4);
    unsigned short* h2s = h0s;  // h0s dead after k_agg1

    hipMemsetAsync(deg, 0, (size_t)N * 4, stream);
    hipMemsetAsync(cur, 0, (size_t)N * 4, stream);

    k_wswz<<<32, 256, 0, stream>>>(W1, wswz);
    k_deg <<<(E + 255) / 256, 256, 0, stream>>>(edst_in, deg, E);
    k_bsum <<<nb, 256, 0, stream>>>(deg, bsum, N);
    k_scan2<<<1, 1024, 0, stream>>>(bsum, bpre, offs + N, nb);
    k_scan3<<<nb, 256, 0, stream>>>(deg, bpre, offs, N);
    k_dinv<<<(N + 255) / 256, 256, 0, stream>>>(deg, dinv, N);
    k_fill<<<(E + 255) / 256, 256, 0, stream>>>(esrc_in, edst_in, offs, cur, esrc, E);

    k_gemm1<<<(N + 127) / 128, 256, 0, stream>>>(x, wswz, dinv, h0s, N);
    k_agg1 <<<(N + 3) / 4, 256, 0, stream>>>(h0s, dinv, offs, esrc, b1, h1, N);
    k_gemm2<<<(N + 255) / 256, 256, 0, stream>>>(h1, W2, dinv, h2s, N);
    k_agg2 <<<(N + 3) / 4, 256, 0, stream>>>(h2s, dinv, offs, esrc, b2, out, N);
}

// Round 9
// 462.479 us; speedup vs baseline: 1.0062x; 1.0062x over previous
//
#include <hip/hip_runtime.h>
#include <hip/hip_bf16.h>
#include <math.h>

typedef __attribute__((ext_vector_type(8))) short short8v;
typedef __attribute__((ext_vector_type(4))) unsigned short ushort4v;
typedef __attribute__((ext_vector_type(8))) unsigned short ushort8v;
typedef __attribute__((ext_vector_type(4))) unsigned uint4v;
typedef __attribute__((ext_vector_type(4))) float f32x4;

__device__ inline unsigned short f2bf(float f) {  // RNE
    unsigned u = __float_as_uint(f);
    return (unsigned short)((u + 0x7fffu + ((u >> 16) & 1u)) >> 16);
}
__device__ inline float bflo(unsigned u) { return __uint_as_float(u << 16); }
__device__ inline float bfhi(unsigned u) { return __uint_as_float(u & 0xffff0000u); }
__device__ inline float bf1(unsigned short s) { return __uint_as_float((unsigned)s << 16); }
__device__ inline unsigned pk2(float a, float b) {  // packed f32x2 -> bf16x2 (RNE), a=low
    __hip_bfloat162 h = __float22bfloat162_rn(make_float2(a, b));
    unsigned r;
    __builtin_memcpy(&r, &h, 4);
    return r;
}

// ---------------------------------------------------------------------------
// CSR build
// ---------------------------------------------------------------------------
__global__ void k_deg(const int* __restrict__ dst, int* __restrict__ deg, int E) {
    int e = blockIdx.x * blockDim.x + threadIdx.x;
    if (e < E) atomicAdd(&deg[dst[e]], 1);
}

__global__ void k_dinv(const int* __restrict__ deg, float* __restrict__ dinv, int N) {
    int i = blockIdx.x * blockDim.x + threadIdx.x;
    if (i < N) dinv[i] = rsqrtf((float)(deg[i] + 1));  // +1 self loop
}

// --- hierarchical exclusive scan: 1024-elem tiles ---------------------------
__global__ __launch_bounds__(256) void k_bsum(const int* __restrict__ deg,
                                              int* __restrict__ bsum, int n) {
    __shared__ int r[256];
    int b = blockIdx.x, tid = threadIdx.x;
    int i0 = b * 1024 + tid * 4;
    int s = 0;
#pragma unroll
    for (int j = 0; j < 4; ++j)
        if (i0 + j < n) s += deg[i0 + j];
    r[tid] = s;
    __syncthreads();
    for (int off = 128; off > 0; off >>= 1) {
        if (tid < off) r[tid] += r[tid + off];
        __syncthreads();
    }
    if (tid == 0) bsum[b] = r[0];
}

__global__ __launch_bounds__(1024) void k_scan2(const int* __restrict__ bsum,
                                                int* __restrict__ bpre,
                                                int* __restrict__ total_out, int nb) {
    __shared__ int ls[1024];
    int tid = threadIdx.x;
    int v = (tid < nb) ? bsum[tid] : 0;
    ls[tid] = v;
    __syncthreads();
    for (int off = 1; off < 1024; off <<= 1) {
        int t = (tid >= off) ? ls[tid - off] : 0;
        __syncthreads();
        ls[tid] += t;
        __syncthreads();
    }
    if (tid < nb) bpre[tid] = ls[tid] - v;
    if (tid == 1023) *total_out = ls[1023];
}

__global__ __launch_bounds__(256) void k_scan3(const int* __restrict__ deg,
                                               const int* __restrict__ bpre,
                                               int* __restrict__ offsets, int n) {
    __shared__ int ts[256];
    int b = blockIdx.x, tid = threadIdx.x;
    int i0 = b * 1024 + tid * 4;
    int v[4] = {0, 0, 0, 0};
#pragma unroll
    for (int j = 0; j < 4; ++j)
        if (i0 + j < n) v[j] = deg[i0 + j];
    int s = v[0] + v[1] + v[2] + v[3];
    ts[tid] = s;
    __syncthreads();
    for (int off = 1; off < 256; off <<= 1) {
        int t = (tid >= off) ? ts[tid - off] : 0;
        __syncthreads();
        ts[tid] += t;
        __syncthreads();
    }
    int excl = bpre[b] + ts[tid] - s;
#pragma unroll
    for (int j = 0; j < 4; ++j) {
        if (i0 + j < n) offsets[i0 + j] = excl;
        excl += v[j];
    }
}

__global__ void k_fill(const int* __restrict__ src, const int* __restrict__ dst,
                       const int* __restrict__ offsets, int* __restrict__ cursor,
                       int* __restrict__ esrc, int E) {
    int e = blockIdx.x * blockDim.x + threadIdx.x;
    if (e < E) {
        int d = dst[e];
        int p = offsets[d] + atomicAdd(&cursor[d], 1);
        esrc[p] = src[e];
    }
}

// ---------------------------------------------------------------------------
// W1 -> bf16, pre-swizzled into per-lane MFMA B-fragment order.
// ---------------------------------------------------------------------------
__global__ void k_wswz(const float* __restrict__ W1, unsigned short* __restrict__ Wswz) {
    int t = blockIdx.x * blockDim.x + threadIdx.x;
    if (t >= 16 * 8 * 64) return;
    int l = t & 63, cb = (t >> 6) & 7, ks = t >> 9;
    int col = cb * 16 + (l & 15);
    int kb = ks * 32 + 8 * (l >> 4);
    ushort8v w;
#pragma unroll
    for (int j = 0; j < 8; ++j) w[j] = f2bf(W1[(size_t)(kb + j) * 128 + col]);
    *(ushort8v*)(Wswz + (size_t)t * 8) = w;
}

// ---------------------------------------------------------------------------
// GEMM1: h0s[M,128](bf16) = dinv[i] * (x[i,:] @ W1)  -- row-prescaled output.
// 128x128 tile, BK=32, 4 waves 2x2, mfma_f32_16x16x32_bf16. (R4 structure.)
// ---------------------------------------------------------------------------
#define GP 40   // As pitch (shorts)
#define CP 132  // Ct pitch (shorts)

__global__ __launch_bounds__(256) void k_gemm1(const float* __restrict__ x,
                                               const unsigned short* __restrict__ Wswz,
                                               const float* __restrict__ dinv,
                                               unsigned short* __restrict__ h0s, int M) {
    __shared__ __align__(16) unsigned short lds[128 * CP];
    unsigned short* As = lds;
    int tid = threadIdx.x;
    int wid = tid >> 6, lane = tid & 63;
    int wr = wid >> 1, wc = wid & 1;
    int g = lane >> 4, lr = lane & 15;
    int brow = blockIdx.x * 128;

    f32x4 acc[4][4];
#pragma unroll
    for (int m = 0; m < 4; ++m)
#pragma unroll
        for (int n = 0; n < 4; ++n) acc[m][n] = (f32x4){0.f, 0.f, 0.f, 0.f};

    for (int k0 = 0; k0 < 512; k0 += 32) {
        float4 st[4];
#pragma unroll
        for (int i = 0; i < 4; ++i) {
            int idx = tid + 256 * i;
            int row = idx >> 3, q = idx & 7;
            int gr = brow + row;
            st[i] = (gr < M) ? *(const float4*)(x + (size_t)gr * 512 + k0 + q * 4)
                             : make_float4(0.f, 0.f, 0.f, 0.f);
        }
        __syncthreads();  // previous iter's fragment reads done
#pragma unroll
        for (int i = 0; i < 4; ++i) {
            int idx = tid + 256 * i;
            int row = idx >> 3, q = idx & 7;
            union { unsigned u[2]; ushort4v s; } w;
            w.u[0] = pk2(st[i].x, st[i].y);
            w.u[1] = pk2(st[i].z, st[i].w);
            *(ushort4v*)&As[row * GP + q * 4] = w.s;
        }
        __syncthreads();
        int ks = k0 >> 5;
        short8v bfr[4];
#pragma unroll
        for (int n = 0; n < 4; ++n) {
            int cb = wc * 4 + n;
            bfr[n] = *(const short8v*)(Wswz + (size_t)((ks * 8 + cb) * 64 + lane) * 8);
        }
        short8v afr[4];
#pragma unroll
        for (int m = 0; m < 4; ++m) {
            int row = wr * 64 + m * 16 + lr;
            afr[m] = *(const short8v*)&As[row * GP + g * 8];
        }
#pragma unroll
        for (int m = 0; m < 4; ++m)
#pragma unroll
            for (int n = 0; n < 4; ++n)
                acc[m][n] = __builtin_amdgcn_mfma_f32_16x16x32_bf16(afr[m], bfr[n],
                                                                    acc[m][n], 0, 0, 0);
    }
    __syncthreads();
    // C/D: col = l&15, row = 4*(l>>4)+reg ; scale by dinv[row] then bf16-stage
#pragma unroll
    for (int m = 0; m < 4; ++m) {
        int row0 = wr * 64 + m * 16 + g * 4;
        float dv[4];
#pragma unroll
        for (int r = 0; r < 4; ++r) {
            int gr = brow + row0 + r;
            dv[r] = (gr < M) ? dinv[gr] : 0.f;
        }
#pragma unroll
        for (int n = 0; n < 4; ++n) {
            int col = wc * 64 + n * 16 + lr;
#pragma unroll
            for (int r = 0; r < 4; ++r)
                lds[(row0 + r) * CP + col] = f2bf(acc[m][n][r] * dv[r]);
        }
    }
    __syncthreads();
    {
        int row = tid >> 1, half = tid & 1;
        int gr = brow + row;
        if (gr < M) {
            unsigned short* dst = h0s + (size_t)gr * 128 + half * 64;
            const unsigned short* src = &lds[row * CP + half * 64];
#pragma unroll
            for (int i = 0; i < 16; ++i)
                *(ushort4v*)(dst + i * 4) = *(const ushort4v*)(src + i * 4);
        }
    }
}

// ---------------------------------------------------------------------------
// Aggregation 1: h1b[i] = bf16( relu( dinv[i]*(h0s[i] + sum_e h0s[src]) + b1 ) )
// ---------------------------------------------------------------------------
__global__ __launch_bounds__(256) void k_agg1(const unsigned short* __restrict__ h0s,
                                              const float* __restrict__ dinv,
                                              const int* __restrict__ offsets,
                                              const int* __restrict__ esrc,
                                              const float* __restrict__ b1,
                                              unsigned* __restrict__ h1b, int N) {
    int wid = (blockIdx.x * 256 + threadIdx.x) >> 6;
    if (wid >= N) return;
    int lane = threadIdx.x & 63;
    const unsigned* base = (const unsigned*)h0s;  // row i = base + i*64
    unsigned us = base[(size_t)wid * 64 + lane];
    float ax = bflo(us), ay = bfhi(us);           // self term (prescaled)
    int beg = offsets[wid], end = offsets[wid + 1];
    for (int b0 = beg; b0 < end; b0 += 64) {
        int nb = min(64, end - b0);
        int idx = (lane < nb) ? esrc[b0 + lane] : 0;
        int k = 0;
        for (; k + 8 <= nb; k += 8) {
            unsigned v[8];
#pragma unroll
            for (int j = 0; j < 8; ++j) {
                int s = __shfl(idx, k + j);
                v[j] = base[(size_t)s * 64 + lane];
            }
#pragma unroll
            for (int j = 0; j < 8; ++j) {
                ax += bflo(v[j]);
                ay += bfhi(v[j]);
            }
        }
        for (; k + 4 <= nb; k += 4) {
            int s0 = __shfl(idx, k + 0), s1 = __shfl(idx, k + 1);
            int s2 = __shfl(idx, k + 2), s3 = __shfl(idx, k + 3);
            unsigned v0 = base[(size_t)s0 * 64 + lane];
            unsigned v1 = base[(size_t)s1 * 64 + lane];
            unsigned v2 = base[(size_t)s2 * 64 + lane];
            unsigned v3 = base[(size_t)s3 * 64 + lane];
            ax += (bflo(v0) + bflo(v1)) + (bflo(v2) + bflo(v3));
            ay += (bfhi(v0) + bfhi(v1)) + (bfhi(v2) + bfhi(v3));
        }
        for (; k < nb; ++k) {
            int s = __shfl(idx, k);
            unsigned v = base[(size_t)s * 64 + lane];
            ax += bflo(v);
            ay += bfhi(v);
        }
    }
    float di = dinv[wid];
    float2 bb = ((const float2*)b1)[lane];
    float rx = fmaxf(fmaf(di, ax, bb.x), 0.f);
    float ry = fmaxf(fmaf(di, ay, bb.y), 0.f);
    h1b[(size_t)wid * 64 + lane] = pk2(rx, ry);
}

// ---------------------------------------------------------------------------
// GEMM2: h2s[M,40](bf16) = dinv[r] * (h1b[r,:] @ W2). Row per thread, W2 in LDS.
// K=128 = 16 uint4v groups x 8 bf16 elements.  (R6-R8 bug: bound was 8 -> only
// half the dot product was accumulated.)
// ---------------------------------------------------------------------------
__global__ __launch_bounds__(256) void k_gemm2(const unsigned* __restrict__ h1b,
                                               const float* __restrict__ W2,
                                               const float* __restrict__ dinv,
                                               unsigned short* __restrict__ h2s, int N) {
    __shared__ float w2s[128 * 40];
    int tid = threadIdx.x;
    for (int i = tid; i < 128 * 40; i += 256) w2s[i] = W2[i];
    __syncthreads();
    int r = blockIdx.x * 256 + tid;
    if (r >= N) return;
    const uint4v* row = (const uint4v*)(h1b + (size_t)r * 64);
    float acc[40];
#pragma unroll
    for (int c = 0; c < 40; ++c) acc[c] = 0.f;
    for (int c8 = 0; c8 < 16; ++c8) {   // 16 groups x 8 elems = full K=128
        uint4v u = row[c8];
        float aa[8];
#pragma unroll
        for (int j = 0; j < 4; ++j) {
            aa[2 * j]     = bflo(u[j]);
            aa[2 * j + 1] = bfhi(u[j]);
        }
        int kb = c8 * 8;
#pragma unroll
        for (int kk = 0; kk < 8; ++kk) {
            float av = aa[kk];
            const float4* wr = (const float4*)&w2s[(kb + kk) * 40];
#pragma unroll
            for (int c4 = 0; c4 < 10; ++c4) {
                float4 w = wr[c4];
                acc[c4 * 4 + 0] = fmaf(av, w.x, acc[c4 * 4 + 0]);
                acc[c4 * 4 + 1] = fmaf(av, w.y, acc[c4 * 4 + 1]);
                acc[c4 * 4 + 2] = fmaf(av, w.z, acc[c4 * 4 + 2]);
                acc[c4 * 4 + 3] = fmaf(av, w.w, acc[c4 * 4 + 3]);
            }
        }
    }
    float di = dinv[r];
    unsigned short* op = h2s + (size_t)r * 40;
#pragma unroll
    for (int c4 = 0; c4 < 10; ++c4) {
        ushort4v w;
        w[0] = f2bf(acc[c4 * 4 + 0] * di); w[1] = f2bf(acc[c4 * 4 + 1] * di);
        w[2] = f2bf(acc[c4 * 4 + 2] * di); w[3] = f2bf(acc[c4 * 4 + 3] * di);
        *(ushort4v*)(op + c4 * 4) = w;
    }
}

// ---------------------------------------------------------------------------
// Aggregation 2 + bias + log_softmax.
// ---------------------------------------------------------------------------
__global__ __launch_bounds__(256) void k_agg2(const unsigned short* __restrict__ h2s,
                                              const float* __restrict__ dinv,
                                              const int* __restrict__ offsets,
                                              const int* __restrict__ esrc,
                                              const float* __restrict__ b2,
                                              float* __restrict__ out, int N) {
    int wid = (blockIdx.x * 256 + threadIdx.x) >> 6;
    if (wid >= N) return;
    int lane = threadIdx.x & 63;
    bool act = lane < 40;
    float acc = act ? bf1(h2s[(size_t)wid * 40 + lane]) : 0.f;  // self (prescaled)
    int beg = offsets[wid], end = offsets[wid + 1];
    for (int b0 = beg; b0 < end; b0 += 64) {
        int nb = min(64, end - b0);
        int idx = (lane < nb) ? esrc[b0 + lane] : 0;
        int k = 0;
        for (; k + 8 <= nb; k += 8) {
            float u[8];
#pragma unroll
            for (int j = 0; j < 8; ++j) {
                int s = __shfl(idx, k + j);
                u[j] = act ? bf1(h2s[(size_t)s * 40 + lane]) : 0.f;
            }
            acc += ((u[0] + u[1]) + (u[2] + u[3])) + ((u[4] + u[5]) + (u[6] + u[7]));
        }
        for (; k + 4 <= nb; k += 4) {
            int s0 = __shfl(idx, k + 0), s1 = __shfl(idx, k + 1);
            int s2 = __shfl(idx, k + 2), s3 = __shfl(idx, k + 3);
            float u0 = act ? bf1(h2s[(size_t)s0 * 40 + lane]) : 0.f;
            float u1 = act ? bf1(h2s[(size_t)s1 * 40 + lane]) : 0.f;
            float u2 = act ? bf1(h2s[(size_t)s2 * 40 + lane]) : 0.f;
            float u3 = act ? bf1(h2s[(size_t)s3 * 40 + lane]) : 0.f;
            acc += (u0 + u1) + (u2 + u3);
        }
        for (; k < nb; ++k) {
            int s = __shfl(idx, k);
            acc += act ? bf1(h2s[(size_t)s * 40 + lane]) : 0.f;
        }
    }
    float di = dinv[wid];
    float logit = fmaf(di, acc, act ? b2[lane] : 0.f);
    float m = act ? logit : -1e30f;
#pragma unroll
    for (int o = 32; o > 0; o >>= 1) m = fmaxf(m, __shfl_xor(m, o));
    float pv = act ? __expf(logit - m) : 0.f;
    float ssum = pv;
#pragma unroll
    for (int o = 32; o > 0; o >>= 1) ssum += __shfl_xor(ssum, o);
    if (act) out[(size_t)wid * 40 + lane] = logit - m - __logf(ssum);
}

extern "C" void kernel_launch(void* const* d_in, const int* in_sizes, int n_in,
                              void* d_out, int out_size, void* d_ws, size_t ws_size,
                              hipStream_t stream) {
    const float* x  = (const float*)d_in[0];
    const int*   ei = (const int*)d_in[1];
    const float* W1 = (const float*)d_in[2];
    const float* b1 = (const float*)d_in[3];
    const float* W2 = (const float*)d_in[4];
    const float* b2 = (const float*)d_in[5];
    float* out = (float*)d_out;

    int N = in_sizes[0] / 512;
    int E = in_sizes[1] / 2;
    const int* esrc_in = ei;
    const int* edst_in = ei + E;
    int nb = (N + 1023) / 1024;  // scan tiles

    char* p = (char*)d_ws;
    size_t off = 0;
    auto take = [&](size_t bytes) {
        size_t o = (off + 255) & ~(size_t)255;
        off = o + bytes;
        return (void*)(p + o);
    };
    unsigned short* h0s  = (unsigned short*)take((size_t)N * 128 * 2);  // bf16 prescaled
    unsigned*       h1b  = (unsigned*)take((size_t)N * 64 * 4);         // bf16x2 packed
    unsigned short* wswz = (unsigned short*)take((size_t)16 * 8 * 64 * 8 * 2);
    int*   deg  = (int*)take((size_t)N * 4);
    float* dinv = (float*)take((size_t)N * 4);
    int*   offs = (int*)take((size_t)(N + 1) * 4);
    int*   cur  = (int*)take((size_t)N * 4);
    int*   bsum = (int*)take((size_t)nb * 4);
    int*   bpre = (int*)take((size_t)nb * 4);
    int*   esrc = (int*)take((size_t)E * 4);
    unsigned short* h2s = h0s;  // h0s dead after k_agg1

    hipMemsetAsync(deg, 0, (size_t)N * 4, stream);
    hipMemsetAsync(cur, 0, (size_t)N * 4, stream);

    k_wswz<<<32, 256, 0, stream>>>(W1, wswz);
    k_deg <<<(E + 255) / 256, 256, 0, stream>>>(edst_in, deg, E);
    k_bsum <<<nb, 256, 0, stream>>>(deg, bsum, N);
    k_scan2<<<1, 1024, 0, stream>>>(bsum, bpre, offs + N, nb);
    k_scan3<<<nb, 256, 0, stream>>>(deg, bpre, offs, N);
    k_dinv<<<(N + 255) / 256, 256, 0, stream>>>(deg, dinv, N);
    k_fill<<<(E + 255) / 256, 256, 0, stream>>>(esrc_in, edst_in, offs, cur, esrc, E);

    k_gemm1<<<(N + 127) / 128, 256, 0, stream>>>(x, wswz, dinv, h0s, N);
    k_agg1 <<<(N + 3) / 4, 256, 0, stream>>>(h0s, dinv, offs, esrc, b1, h1b, N);
    k_gemm2<<<(N + 255) / 256, 256, 0, stream>>>(h1b, W2, dinv, h2s, N);
    k_agg2 <<<(N + 3) / 4, 256, 0, stream>>>(h2s, dinv, offs, esrc, b2, out, N);
}

// Round 10
// 418.520 us; speedup vs baseline: 1.1118x; 1.1050x over previous
//
#include <hip/hip_runtime.h>
#include <hip/hip_bf16.h>
#include <math.h>

typedef __attribute__((ext_vector_type(8))) short short8v;
typedef __attribute__((ext_vector_type(4))) unsigned short ushort4v;
typedef __attribute__((ext_vector_type(8))) unsigned short ushort8v;
typedef __attribute__((ext_vector_type(4))) unsigned uint4v;
typedef __attribute__((ext_vector_type(4))) float f32x4;

__device__ inline unsigned short f2bf(float f) {  // RNE
    unsigned u = __float_as_uint(f);
    return (unsigned short)((u + 0x7fffu + ((u >> 16) & 1u)) >> 16);
}
__device__ inline float bflo(unsigned u) { return __uint_as_float(u << 16); }
__device__ inline float bfhi(unsigned u) { return __uint_as_float(u & 0xffff0000u); }
__device__ inline float bf1(unsigned short s) { return __uint_as_float((unsigned)s << 16); }
__device__ inline unsigned pk2(float a, float b) {  // packed f32x2 -> bf16x2 (RNE), a=low
    __hip_bfloat162 h = __float22bfloat162_rn(make_float2(a, b));
    unsigned r;
    __builtin_memcpy(&r, &h, 4);
    return r;
}

// ---------------------------------------------------------------------------
// CSR build
// ---------------------------------------------------------------------------
__global__ void k_deg(const int* __restrict__ dst, int* __restrict__ deg, int E) {
    int e = blockIdx.x * blockDim.x + threadIdx.x;
    if (e < E) atomicAdd(&deg[dst[e]], 1);
}

__global__ void k_dinv(const int* __restrict__ deg, float* __restrict__ dinv, int N) {
    int i = blockIdx.x * blockDim.x + threadIdx.x;
    if (i < N) dinv[i] = rsqrtf((float)(deg[i] + 1));  // +1 self loop
}

// --- hierarchical exclusive scan: 1024-elem tiles ---------------------------
__global__ __launch_bounds__(256) void k_bsum(const int* __restrict__ deg,
                                              int* __restrict__ bsum, int n) {
    __shared__ int r[256];
    int b = blockIdx.x, tid = threadIdx.x;
    int i0 = b * 1024 + tid * 4;
    int s = 0;
#pragma unroll
    for (int j = 0; j < 4; ++j)
        if (i0 + j < n) s += deg[i0 + j];
    r[tid] = s;
    __syncthreads();
    for (int off = 128; off > 0; off >>= 1) {
        if (tid < off) r[tid] += r[tid + off];
        __syncthreads();
    }
    if (tid == 0) bsum[b] = r[0];
}

__global__ __launch_bounds__(1024) void k_scan2(const int* __restrict__ bsum,
                                                int* __restrict__ bpre,
                                                int* __restrict__ total_out, int nb) {
    __shared__ int ls[1024];
    int tid = threadIdx.x;
    int v = (tid < nb) ? bsum[tid] : 0;
    ls[tid] = v;
    __syncthreads();
    for (int off = 1; off < 1024; off <<= 1) {
        int t = (tid >= off) ? ls[tid - off] : 0;
        __syncthreads();
        ls[tid] += t;
        __syncthreads();
    }
    if (tid < nb) bpre[tid] = ls[tid] - v;
    if (tid == 1023) *total_out = ls[1023];
}

__global__ __launch_bounds__(256) void k_scan3(const int* __restrict__ deg,
                                               const int* __restrict__ bpre,
                                               int* __restrict__ offsets, int n) {
    __shared__ int ts[256];
    int b = blockIdx.x, tid = threadIdx.x;
    int i0 = b * 1024 + tid * 4;
    int v[4] = {0, 0, 0, 0};
#pragma unroll
    for (int j = 0; j < 4; ++j)
        if (i0 + j < n) v[j] = deg[i0 + j];
    int s = v[0] + v[1] + v[2] + v[3];
    ts[tid] = s;
    __syncthreads();
    for (int off = 1; off < 256; off <<= 1) {
        int t = (tid >= off) ? ts[tid - off] : 0;
        __syncthreads();
        ts[tid] += t;
        __syncthreads();
    }
    int excl = bpre[b] + ts[tid] - s;
#pragma unroll
    for (int j = 0; j < 4; ++j) {
        if (i0 + j < n) offsets[i0 + j] = excl;
        excl += v[j];
    }
}

__global__ void k_fill(const int* __restrict__ src, const int* __restrict__ dst,
                       const int* __restrict__ offsets, int* __restrict__ cursor,
                       int* __restrict__ esrc, int E) {
    int e = blockIdx.x * blockDim.x + threadIdx.x;
    if (e < E) {
        int d = dst[e];
        int p = offsets[d] + atomicAdd(&cursor[d], 1);
        esrc[p] = src[e];
    }
}

// ---------------------------------------------------------------------------
// W1 -> bf16, pre-swizzled into per-lane MFMA B-fragment order.
// ---------------------------------------------------------------------------
__global__ void k_wswz(const float* __restrict__ W1, unsigned short* __restrict__ Wswz) {
    int t = blockIdx.x * blockDim.x + threadIdx.x;
    if (t >= 16 * 8 * 64) return;
    int l = t & 63, cb = (t >> 6) & 7, ks = t >> 9;
    int col = cb * 16 + (l & 15);
    int kb = ks * 32 + 8 * (l >> 4);
    ushort8v w;
#pragma unroll
    for (int j = 0; j < 8; ++j) w[j] = f2bf(W1[(size_t)(kb + j) * 128 + col]);
    *(ushort8v*)(Wswz + (size_t)t * 8) = w;
}

// ---------------------------------------------------------------------------
// GEMM1: h0s[M,128](bf16) = dinv[i] * (x[i,:] @ W1).
// 64x128 tile (grid ~1563 -> ~6 blocks/CU), 4 waves side-by-side in N.
// Reg-staged A with packed cvt + register prefetch of next K-step issued
// before the bfr/afr/MFMA phase (hides load latency under compute).
// Output h0s proven byte-identical to the 128x128 structure (R6-R8 absmax
// equality); epilogue LDS reads kept at 8B (264B row pitch, R6 lesson).
// ---------------------------------------------------------------------------
#define AP 40   // As pitch (shorts)
#define CP 132  // epilogue transpose pitch (shorts)

__global__ __launch_bounds__(256) void k_gemm1(const float* __restrict__ x,
                                               const unsigned short* __restrict__ Wswz,
                                               const float* __restrict__ dinv,
                                               unsigned short* __restrict__ h0s, int M) {
    __shared__ __align__(16) unsigned short lds[64 * CP];  // union: As(64xAP)/Ct(64xCP)
    unsigned short* As = lds;
    int tid = threadIdx.x;
    int wc = tid >> 6, lane = tid & 63;       // wave wc covers cols wc*32..+32
    int g = lane >> 4, lr = lane & 15;
    int brow = blockIdx.x * 64;

    int srow = tid >> 2, sq = tid & 3;        // staging: row 0..63, quarter 0..3
    int sgr = brow + srow;
    const float* xp = (sgr < M) ? (x + (size_t)sgr * 512 + sq * 8) : nullptr;

    f32x4 acc[4][2];
#pragma unroll
    for (int m = 0; m < 4; ++m)
#pragma unroll
        for (int n = 0; n < 2; ++n) acc[m][n] = (f32x4){0.f, 0.f, 0.f, 0.f};

    float4 pa = make_float4(0.f, 0.f, 0.f, 0.f);
    float4 pb = make_float4(0.f, 0.f, 0.f, 0.f);
    if (xp) { pa = *(const float4*)xp; pb = *(const float4*)(xp + 4); }

    for (int ks = 0; ks < 16; ++ks) {
        union { uint4v u; short8v s; } cv;
        cv.u[0] = pk2(pa.x, pa.y);
        cv.u[1] = pk2(pa.z, pa.w);
        cv.u[2] = pk2(pb.x, pb.y);
        cv.u[3] = pk2(pb.z, pb.w);
        __syncthreads();  // previous iter's fragment reads done
        *(short8v*)&As[srow * AP + sq * 8] = cv.s;
        __syncthreads();
        if (ks < 15 && xp) {  // prefetch next K-step; hides under ds_read+MFMA
            const float* np = xp + (ks + 1) * 32;
            pa = *(const float4*)np;
            pb = *(const float4*)(np + 4);
        }
        short8v bfr[2];
#pragma unroll
        for (int n = 0; n < 2; ++n) {
            int cb = wc * 2 + n;
            bfr[n] = *(const short8v*)(Wswz + (size_t)((ks * 8 + cb) * 64 + lane) * 8);
        }
        short8v afr[4];
#pragma unroll
        for (int m = 0; m < 4; ++m)
            afr[m] = *(const short8v*)&As[(m * 16 + lr) * AP + g * 8];
#pragma unroll
        for (int m = 0; m < 4; ++m)
#pragma unroll
            for (int n = 0; n < 2; ++n)
                acc[m][n] = __builtin_amdgcn_mfma_f32_16x16x32_bf16(afr[m], bfr[n],
                                                                    acc[m][n], 0, 0, 0);
    }
    __syncthreads();  // last reads of As done; lds becomes Ct
    // C/D: col = l&15, row = 4*(l>>4)+reg ; scale by dinv[row], stage transpose
#pragma unroll
    for (int m = 0; m < 4; ++m) {
        int row0 = m * 16 + g * 4;
        float dv[4];
#pragma unroll
        for (int r = 0; r < 4; ++r) {
            int gr = brow + row0 + r;
            dv[r] = (gr < M) ? dinv[gr] : 0.f;
        }
#pragma unroll
        for (int n = 0; n < 2; ++n) {
            int col = wc * 32 + n * 16 + lr;
#pragma unroll
            for (int r = 0; r < 4; ++r)
                lds[(row0 + r) * CP + col] = f2bf(acc[m][n][r] * dv[r]);
        }
    }
    __syncthreads();
    if (sgr < M) {
        unsigned short* dst = h0s + (size_t)sgr * 128;
        const unsigned short* src = &lds[srow * CP];
#pragma unroll
        for (int i = 0; i < 4; ++i) {
            int c = i * 32 + sq * 8;
            *(ushort4v*)(dst + c)     = *(const ushort4v*)(src + c);      // 8B reads:
            *(ushort4v*)(dst + c + 4) = *(const ushort4v*)(src + c + 4);  // pitch-safe
        }
    }
}

// ---------------------------------------------------------------------------
// Aggregation 1: h1b[i] = bf16( relu( dinv[i]*(h0s[i] + sum_e h0s[src]) + b1 ) )
// ---------------------------------------------------------------------------
__global__ __launch_bounds__(256) void k_agg1(const unsigned short* __restrict__ h0s,
                                              const float* __restrict__ dinv,
                                              const int* __restrict__ offsets,
                                              const int* __restrict__ esrc,
                                              const float* __restrict__ b1,
                                              unsigned* __restrict__ h1b, int N) {
    int wid = (blockIdx.x * 256 + threadIdx.x) >> 6;
    if (wid >= N) return;
    int lane = threadIdx.x & 63;
    const unsigned* base = (const unsigned*)h0s;  // row i = base + i*64
    unsigned us = base[(size_t)wid * 64 + lane];
    float ax = bflo(us), ay = bfhi(us);           // self term (prescaled)
    int beg = offsets[wid], end = offsets[wid + 1];
    for (int b0 = beg; b0 < end; b0 += 64) {
        int nb = min(64, end - b0);
        int idx = (lane < nb) ? esrc[b0 + lane] : 0;
        int k = 0;
        for (; k + 8 <= nb; k += 8) {
            unsigned v[8];
#pragma unroll
            for (int j = 0; j < 8; ++j) {
                int s = __shfl(idx, k + j);
                v[j] = base[(size_t)s * 64 + lane];
            }
#pragma unroll
            for (int j = 0; j < 8; ++j) {
                ax += bflo(v[j]);
                ay += bfhi(v[j]);
            }
        }
        for (; k + 4 <= nb; k += 4) {
            int s0 = __shfl(idx, k + 0), s1 = __shfl(idx, k + 1);
            int s2 = __shfl(idx, k + 2), s3 = __shfl(idx, k + 3);
            unsigned v0 = base[(size_t)s0 * 64 + lane];
            unsigned v1 = base[(size_t)s1 * 64 + lane];
            unsigned v2 = base[(size_t)s2 * 64 + lane];
            unsigned v3 = base[(size_t)s3 * 64 + lane];
            ax += (bflo(v0) + bflo(v1)) + (bflo(v2) + bflo(v3));
            ay += (bfhi(v0) + bfhi(v1)) + (bfhi(v2) + bfhi(v3));
        }
        for (; k < nb; ++k) {
            int s = __shfl(idx, k);
            unsigned v = base[(size_t)s * 64 + lane];
            ax += bflo(v);
            ay += bfhi(v);
        }
    }
    float di = dinv[wid];
    float2 bb = ((const float2*)b1)[lane];
    float rx = fmaxf(fmaf(di, ax, bb.x), 0.f);
    float ry = fmaxf(fmaf(di, ay, bb.y), 0.f);
    h1b[(size_t)wid * 64 + lane] = pk2(rx, ry);
}

// ---------------------------------------------------------------------------
// GEMM2: h2s[M,40](bf16) = dinv[r] * (h1b[r,:] @ W2). Row per thread, W2 in LDS.
// K=128 = 16 uint4v groups x 8 bf16 elements.
// ---------------------------------------------------------------------------
__global__ __launch_bounds__(256) void k_gemm2(const unsigned* __restrict__ h1b,
                                               const float* __restrict__ W2,
                                               const float* __restrict__ dinv,
                                               unsigned short* __restrict__ h2s, int N) {
    __shared__ float w2s[128 * 40];
    int tid = threadIdx.x;
    for (int i = tid; i < 128 * 40; i += 256) w2s[i] = W2[i];
    __syncthreads();
    int r = blockIdx.x * 256 + tid;
    if (r >= N) return;
    const uint4v* row = (const uint4v*)(h1b + (size_t)r * 64);
    float acc[40];
#pragma unroll
    for (int c = 0; c < 40; ++c) acc[c] = 0.f;
    for (int c8 = 0; c8 < 16; ++c8) {   // 16 groups x 8 elems = full K=128
        uint4v u = row[c8];
        float aa[8];
#pragma unroll
        for (int j = 0; j < 4; ++j) {
            aa[2 * j]     = bflo(u[j]);
            aa[2 * j + 1] = bfhi(u[j]);
        }
        int kb = c8 * 8;
#pragma unroll
        for (int kk = 0; kk < 8; ++kk) {
            float av = aa[kk];
            const float4* wr = (const float4*)&w2s[(kb + kk) * 40];
#pragma unroll
            for (int c4 = 0; c4 < 10; ++c4) {
                float4 w = wr[c4];
                acc[c4 * 4 + 0] = fmaf(av, w.x, acc[c4 * 4 + 0]);
                acc[c4 * 4 + 1] = fmaf(av, w.y, acc[c4 * 4 + 1]);
                acc[c4 * 4 + 2] = fmaf(av, w.z, acc[c4 * 4 + 2]);
                acc[c4 * 4 + 3] = fmaf(av, w.w, acc[c4 * 4 + 3]);
            }
        }
    }
    float di = dinv[r];
    unsigned short* op = h2s + (size_t)r * 40;
#pragma unroll
    for (int c4 = 0; c4 < 10; ++c4) {
        ushort4v w;
        w[0] = f2bf(acc[c4 * 4 + 0] * di); w[1] = f2bf(acc[c4 * 4 + 1] * di);
        w[2] = f2bf(acc[c4 * 4 + 2] * di); w[3] = f2bf(acc[c4 * 4 + 3] * di);
        *(ushort4v*)(op + c4 * 4) = w;
    }
}

// ---------------------------------------------------------------------------
// Aggregation 2 + bias + log_softmax.
// ---------------------------------------------------------------------------
__global__ __launch_bounds__(256) void k_agg2(const unsigned short* __restrict__ h2s,
                                              const float* __restrict__ dinv,
                                              const int* __restrict__ offsets,
                                              const int* __restrict__ esrc,
                                              const float* __restrict__ b2,
                                              float* __restrict__ out, int N) {
    int wid = (blockIdx.x * 256 + threadIdx.x) >> 6;
    if (wid >= N) return;
    int lane = threadIdx.x & 63;
    bool act = lane < 40;
    float acc = act ? bf1(h2s[(size_t)wid * 40 + lane]) : 0.f;  // self (prescaled)
    int beg = offsets[wid], end = offsets[wid + 1];
    for (int b0 = beg; b0 < end; b0 += 64) {
        int nb = min(64, end - b0);
        int idx = (lane < nb) ? esrc[b0 + lane] : 0;
        int k = 0;
        for (; k + 8 <= nb; k += 8) {
            float u[8];
#pragma unroll
            for (int j = 0; j < 8; ++j) {
                int s = __shfl(idx, k + j);
                u[j] = act ? bf1(h2s[(size_t)s * 40 + lane]) : 0.f;
            }
            acc += ((u[0] + u[1]) + (u[2] + u[3])) + ((u[4] + u[5]) + (u[6] + u[7]));
        }
        for (; k + 4 <= nb; k += 4) {
            int s0 = __shfl(idx, k + 0), s1 = __shfl(idx, k + 1);
            int s2 = __shfl(idx, k + 2), s3 = __shfl(idx, k + 3);
            float u0 = act ? bf1(h2s[(size_t)s0 * 40 + lane]) : 0.f;
            float u1 = act ? bf1(h2s[(size_t)s1 * 40 + lane]) : 0.f;
            float u2 = act ? bf1(h2s[(size_t)s2 * 40 + lane]) : 0.f;
            float u3 = act ? bf1(h2s[(size_t)s3 * 40 + lane]) : 0.f;
            acc += (u0 + u1) + (u2 + u3);
        }
        for (; k < nb; ++k) {
            int s = __shfl(idx, k);
            acc += act ? bf1(h2s[(size_t)s * 40 + lane]) : 0.f;
        }
    }
    float di = dinv[wid];
    float logit = fmaf(di, acc, act ? b2[lane] : 0.f);
    float m = act ? logit : -1e30f;
#pragma unroll
    for (int o = 32; o > 0; o >>= 1) m = fmaxf(m, __shfl_xor(m, o));
    float pv = act ? __expf(logit - m) : 0.f;
    float ssum = pv;
#pragma unroll
    for (int o = 32; o > 0; o >>= 1) ssum += __shfl_xor(ssum, o);
    if (act) out[(size_t)wid * 40 + lane] = logit - m - __logf(ssum);
}

extern "C" void kernel_launch(void* const* d_in, const int* in_sizes, int n_in,
                              void* d_out, int out_size, void* d_ws, size_t ws_size,
                              hipStream_t stream) {
    const float* x  = (const float*)d_in[0];
    const int*   ei = (const int*)d_in[1];
    const float* W1 = (const float*)d_in[2];
    const float* b1 = (const float*)d_in[3];
    const float* W2 = (const float*)d_in[4];
    const float* b2 = (const float*)d_in[5];
    float* out = (float*)d_out;

    int N = in_sizes[0] / 512;
    int E = in_sizes[1] / 2;
    const int* esrc_in = ei;
    const int* edst_in = ei + E;
    int nb = (N + 1023) / 1024;  // scan tiles

    char* p = (char*)d_ws;
    size_t off = 0;
    auto take = [&](size_t bytes) {
        size_t o = (off + 255) & ~(size_t)255;
        off = o + bytes;
        return (void*)(p + o);
    };
    unsigned short* h0s  = (unsigned short*)take((size_t)N * 128 * 2);  // bf16 prescaled
    unsigned*       h1b  = (unsigned*)take((size_t)N * 64 * 4);         // bf16x2 packed
    unsigned short* wswz = (unsigned short*)take((size_t)16 * 8 * 64 * 8 * 2);
    int*   deg  = (int*)take((size_t)N * 4);
    float* dinv = (float*)take((size_t)N * 4);
    int*   offs = (int*)take((size_t)(N + 1) * 4);
    int*   cur  = (int*)take((size_t)N * 4);
    int*   bsum = (int*)take((size_t)nb * 4);
    int*   bpre = (int*)take((size_t)nb * 4);
    int*   esrc = (int*)take((size_t)E * 4);
    unsigned short* h2s = h0s;  // h0s dead after k_agg1

    hipMemsetAsync(deg, 0, (size_t)N * 4, stream);
    hipMemsetAsync(cur, 0, (size_t)N * 4, stream);

    k_wswz<<<32, 256, 0, stream>>>(W1, wswz);
    k_deg <<<(E + 255) / 256, 256, 0, stream>>>(edst_in, deg, E);
    k_bsum <<<nb, 256, 0, stream>>>(deg, bsum, N);
    k_scan2<<<1, 1024, 0, stream>>>(bsum, bpre, offs + N, nb);
    k_scan3<<<nb, 256, 0, stream>>>(deg, bpre, offs, N);
    k_dinv<<<(N + 255) / 256, 256, 0, stream>>>(deg, dinv, N);
    k_fill<<<(E + 255) / 256, 256, 0, stream>>>(esrc_in, edst_in, offs, cur, esrc, E);

    k_gemm1<<<(N + 63) / 64, 256, 0, stream>>>(x, wswz, dinv, h0s, N);
    k_agg1 <<<(N + 3) / 4, 256, 0, stream>>>(h0s, dinv, offs, esrc, b1, h1b, N);
    k_gemm2<<<(N + 255) / 256, 256, 0, stream>>>(h1b, W2, dinv, h2s, N);
    k_agg2 <<<(N + 3) / 4, 256, 0, stream>>>(h2s, dinv, offs, esrc, b2, out, N);
}

// Round 11
// 372.087 us; speedup vs baseline: 1.2506x; 1.1248x over previous
//
#include <hip/hip_runtime.h>
#include <hip/hip_bf16.h>
#include <math.h>

typedef __attribute__((ext_vector_type(8))) short short8v;
typedef __attribute__((ext_vector_type(4))) unsigned short ushort4v;
typedef __attribute__((ext_vector_type(8))) unsigned short ushort8v;
typedef __attribute__((ext_vector_type(4))) unsigned uint4v;
typedef __attribute__((ext_vector_type(4))) float f32x4;

__device__ inline unsigned short f2bf(float f) {  // RNE
    unsigned u = __float_as_uint(f);
    return (unsigned short)((u + 0x7fffu + ((u >> 16) & 1u)) >> 16);
}
__device__ inline float bflo(unsigned u) { return __uint_as_float(u << 16); }
__device__ inline float bfhi(unsigned u) { return __uint_as_float(u & 0xffff0000u); }
__device__ inline float bf1(unsigned short s) { return __uint_as_float((unsigned)s << 16); }
__device__ inline unsigned pk2(float a, float b) {  // packed f32x2 -> bf16x2 (RNE), a=low
    __hip_bfloat162 h = __float22bfloat162_rn(make_float2(a, b));
    unsigned r;
    __builtin_memcpy(&r, &h, 4);
    return r;
}

// ---------------------------------------------------------------------------
// CSR build.  k_deg also records each edge's insertion rank so k_fill needs
// no second atomic pass (and no cursor buffer/memset).
// ---------------------------------------------------------------------------
__global__ void k_deg(const int* __restrict__ dst, int* __restrict__ deg,
                      int* __restrict__ rank, int E) {
    int e = blockIdx.x * blockDim.x + threadIdx.x;
    if (e < E) rank[e] = atomicAdd(&deg[dst[e]], 1);
}

// --- hierarchical exclusive scan: 1024-elem tiles ---------------------------
__global__ __launch_bounds__(256) void k_bsum(const int* __restrict__ deg,
                                              int* __restrict__ bsum, int n) {
    __shared__ int r[256];
    int b = blockIdx.x, tid = threadIdx.x;
    int i0 = b * 1024 + tid * 4;
    int s = 0;
#pragma unroll
    for (int j = 0; j < 4; ++j)
        if (i0 + j < n) s += deg[i0 + j];
    r[tid] = s;
    __syncthreads();
    for (int off = 128; off > 0; off >>= 1) {
        if (tid < off) r[tid] += r[tid + off];
        __syncthreads();
    }
    if (tid == 0) bsum[b] = r[0];
}

__global__ __launch_bounds__(1024) void k_scan2(const int* __restrict__ bsum,
                                                int* __restrict__ bpre,
                                                int* __restrict__ total_out, int nb) {
    __shared__ int ls[1024];
    int tid = threadIdx.x;
    int v = (tid < nb) ? bsum[tid] : 0;
    ls[tid] = v;
    __syncthreads();
    for (int off = 1; off < 1024; off <<= 1) {
        int t = (tid >= off) ? ls[tid - off] : 0;
        __syncthreads();
        ls[tid] += t;
        __syncthreads();
    }
    if (tid < nb) bpre[tid] = ls[tid] - v;
    if (tid == 1023) *total_out = ls[1023];
}

// scan3 also emits dinv (deg already in registers here).
__global__ __launch_bounds__(256) void k_scan3(const int* __restrict__ deg,
                                               const int* __restrict__ bpre,
                                               int* __restrict__ offsets,
                                               float* __restrict__ dinv, int n) {
    __shared__ int ts[256];
    int b = blockIdx.x, tid = threadIdx.x;
    int i0 = b * 1024 + tid * 4;
    int v[4] = {0, 0, 0, 0};
#pragma unroll
    for (int j = 0; j < 4; ++j)
        if (i0 + j < n) v[j] = deg[i0 + j];
    int s = v[0] + v[1] + v[2] + v[3];
    ts[tid] = s;
    __syncthreads();
    for (int off = 1; off < 256; off <<= 1) {
        int t = (tid >= off) ? ts[tid - off] : 0;
        __syncthreads();
        ts[tid] += t;
        __syncthreads();
    }
    int excl = bpre[b] + ts[tid] - s;
#pragma unroll
    for (int j = 0; j < 4; ++j) {
        if (i0 + j < n) {
            offsets[i0 + j] = excl;
            dinv[i0 + j] = rsqrtf((float)(v[j] + 1));  // +1 self loop
        }
        excl += v[j];
    }
}

__global__ void k_fill(const int* __restrict__ src, const int* __restrict__ dst,
                       const int* __restrict__ offsets, const int* __restrict__ rank,
                       int* __restrict__ esrc, int E) {
    int e = blockIdx.x * blockDim.x + threadIdx.x;
    if (e < E) esrc[offsets[dst[e]] + rank[e]] = src[e];
}

// ---------------------------------------------------------------------------
// W1 -> bf16, pre-swizzled into per-lane MFMA B-fragment order.
// ---------------------------------------------------------------------------
__global__ void k_wswz(const float* __restrict__ W1, unsigned short* __restrict__ Wswz) {
    int t = blockIdx.x * blockDim.x + threadIdx.x;
    if (t >= 16 * 8 * 64) return;
    int l = t & 63, cb = (t >> 6) & 7, ks = t >> 9;
    int col = cb * 16 + (l & 15);
    int kb = ks * 32 + 8 * (l >> 4);
    ushort8v w;
#pragma unroll
    for (int j = 0; j < 8; ++j) w[j] = f2bf(W1[(size_t)(kb + j) * 128 + col]);
    *(ushort8v*)(Wswz + (size_t)t * 8) = w;
}

// ---------------------------------------------------------------------------
// GEMM1: h0s[M,128](bf16) = dinv[i] * (x[i,:] @ W1).
// 64x128 tile, 4 waves in N; reg-staged A (packed cvt) with register prefetch.
// NEW: double-buffered As -> ONE barrier per K-step (was two).
// Safety: overwrite of As[k&1] at iter k+2 is ordered after sync(k+1), which
// every thread reaches only after its iter-k fragment reads (program order).
// As[2] (2x2560 shorts) fits inside the 8448-short epilogue union; epilogue
// is separated from the last reads by the post-loop barrier.
// ---------------------------------------------------------------------------
#define AP 40   // As pitch (shorts)
#define CP 132  // epilogue transpose pitch (shorts)

__global__ __launch_bounds__(256) void k_gemm1(const float* __restrict__ x,
                                               const unsigned short* __restrict__ Wswz,
                                               const float* __restrict__ dinv,
                                               unsigned short* __restrict__ h0s, int M) {
    __shared__ __align__(16) unsigned short lds[64 * CP];  // As0|As1 / Ct union
    int tid = threadIdx.x;
    int wc = tid >> 6, lane = tid & 63;       // wave wc covers cols wc*32..+32
    int g = lane >> 4, lr = lane & 15;
    int brow = blockIdx.x * 64;

    int srow = tid >> 2, sq = tid & 3;        // staging: row 0..63, quarter 0..3
    int sgr = brow + srow;
    const float* xp = (sgr < M) ? (x + (size_t)sgr * 512 + sq * 8) : nullptr;

    f32x4 acc[4][2];
#pragma unroll
    for (int m = 0; m < 4; ++m)
#pragma unroll
        for (int n = 0; n < 2; ++n) acc[m][n] = (f32x4){0.f, 0.f, 0.f, 0.f};

    float4 pa = make_float4(0.f, 0.f, 0.f, 0.f);
    float4 pb = make_float4(0.f, 0.f, 0.f, 0.f);
    if (xp) { pa = *(const float4*)xp; pb = *(const float4*)(xp + 4); }

    for (int ks = 0; ks < 16; ++ks) {
        unsigned short* As = lds + (ks & 1) * 2560;  // 64*AP per buffer
        union { uint4v u; short8v s; } cv;
        cv.u[0] = pk2(pa.x, pa.y);
        cv.u[1] = pk2(pa.z, pa.w);
        cv.u[2] = pk2(pb.x, pb.y);
        cv.u[3] = pk2(pb.z, pb.w);
        *(short8v*)&As[srow * AP + sq * 8] = cv.s;
        __syncthreads();  // As[ks&1] writes visible; prior buffer reads done
        if (ks < 15 && xp) {  // prefetch next K-step; hides under ds_read+MFMA
            const float* np = xp + (ks + 1) * 32;
            pa = *(const float4*)np;
            pb = *(const float4*)(np + 4);
        }
        short8v bfr[2];
#pragma unroll
        for (int n = 0; n < 2; ++n) {
            int cb = wc * 2 + n;
            bfr[n] = *(const short8v*)(Wswz + (size_t)((ks * 8 + cb) * 64 + lane) * 8);
        }
        short8v afr[4];
#pragma unroll
        for (int m = 0; m < 4; ++m)
            afr[m] = *(const short8v*)&As[(m * 16 + lr) * AP + g * 8];
#pragma unroll
        for (int m = 0; m < 4; ++m)
#pragma unroll
            for (int n = 0; n < 2; ++n)
                acc[m][n] = __builtin_amdgcn_mfma_f32_16x16x32_bf16(afr[m], bfr[n],
                                                                    acc[m][n], 0, 0, 0);
    }
    __syncthreads();  // last As reads done; lds becomes Ct
    // C/D: col = l&15, row = 4*(l>>4)+reg ; scale by dinv[row], stage transpose
#pragma unroll
    for (int m = 0; m < 4; ++m) {
        int row0 = m * 16 + g * 4;
        float dv[4];
#pragma unroll
        for (int r = 0; r < 4; ++r) {
            int gr = brow + row0 + r;
            dv[r] = (gr < M) ? dinv[gr] : 0.f;
        }
#pragma unroll
        for (int n = 0; n < 2; ++n) {
            int col = wc * 32 + n * 16 + lr;
#pragma unroll
            for (int r = 0; r < 4; ++r)
                lds[(row0 + r) * CP + col] = f2bf(acc[m][n][r] * dv[r]);
        }
    }
    __syncthreads();
    if (sgr < M) {
        unsigned short* dst = h0s + (size_t)sgr * 128;
        const unsigned short* src = &lds[srow * CP];
#pragma unroll
        for (int i = 0; i < 4; ++i) {
            int c = i * 32 + sq * 8;
            *(ushort4v*)(dst + c)     = *(const ushort4v*)(src + c);      // 8B reads:
            *(ushort4v*)(dst + c + 4) = *(const ushort4v*)(src + c + 4);  // pitch-safe
        }
    }
}

// ---------------------------------------------------------------------------
// Aggregation 1: h1b[i] = bf16( relu( dinv[i]*(h0s[i] + sum_e h0s[src]) + b1 ) )
// One wave per node; coalesced index prefetch + shfl broadcast; 16x unrolled
// (16 outstanding gathers/wave).
// ---------------------------------------------------------------------------
__global__ __launch_bounds__(256) void k_agg1(const unsigned short* __restrict__ h0s,
                                              const float* __restrict__ dinv,
                                              const int* __restrict__ offsets,
                                              const int* __restrict__ esrc,
                                              const float* __restrict__ b1,
                                              unsigned* __restrict__ h1b, int N) {
    int wid = (blockIdx.x * 256 + threadIdx.x) >> 6;
    if (wid >= N) return;
    int lane = threadIdx.x & 63;
    const unsigned* base = (const unsigned*)h0s;  // row i = base + i*64
    unsigned us = base[(size_t)wid * 64 + lane];
    float ax = bflo(us), ay = bfhi(us);           // self term (prescaled)
    int beg = offsets[wid], end = offsets[wid + 1];
    for (int b0 = beg; b0 < end; b0 += 64) {
        int nb = min(64, end - b0);
        int idx = (lane < nb) ? esrc[b0 + lane] : 0;
        int k = 0;
        for (; k + 16 <= nb; k += 16) {
            unsigned v[16];
#pragma unroll
            for (int j = 0; j < 16; ++j) {
                int s = __shfl(idx, k + j);
                v[j] = base[(size_t)s * 64 + lane];
            }
#pragma unroll
            for (int j = 0; j < 16; ++j) {
                ax += bflo(v[j]);
                ay += bfhi(v[j]);
            }
        }
        for (; k + 4 <= nb; k += 4) {
            int s0 = __shfl(idx, k + 0), s1 = __shfl(idx, k + 1);
            int s2 = __shfl(idx, k + 2), s3 = __shfl(idx, k + 3);
            unsigned v0 = base[(size_t)s0 * 64 + lane];
            unsigned v1 = base[(size_t)s1 * 64 + lane];
            unsigned v2 = base[(size_t)s2 * 64 + lane];
            unsigned v3 = base[(size_t)s3 * 64 + lane];
            ax += (bflo(v0) + bflo(v1)) + (bflo(v2) + bflo(v3));
            ay += (bfhi(v0) + bfhi(v1)) + (bfhi(v2) + bfhi(v3));
        }
        for (; k < nb; ++k) {
            int s = __shfl(idx, k);
            unsigned v = base[(size_t)s * 64 + lane];
            ax += bflo(v);
            ay += bfhi(v);
        }
    }
    float di = dinv[wid];
    float2 bb = ((const float2*)b1)[lane];
    float rx = fmaxf(fmaf(di, ax, bb.x), 0.f);
    float ry = fmaxf(fmaf(di, ay, bb.y), 0.f);
    h1b[(size_t)wid * 64 + lane] = pk2(rx, ry);
}

// ---------------------------------------------------------------------------
// GEMM2: h2s[M,40](bf16) = dinv[r] * (h1b[r,:] @ W2). Row per thread, W2 in LDS.
// K=128 = 16 uint4v groups x 8 bf16 elements.
// ---------------------------------------------------------------------------
__global__ __launch_bounds__(256) void k_gemm2(const unsigned* __restrict__ h1b,
                                               const float* __restrict__ W2,
                                               const float* __restrict__ dinv,
                                               unsigned short* __restrict__ h2s, int N) {
    __shared__ float w2s[128 * 40];
    int tid = threadIdx.x;
    for (int i = tid; i < 128 * 40; i += 256) w2s[i] = W2[i];
    __syncthreads();
    int r = blockIdx.x * 256 + tid;
    if (r >= N) return;
    const uint4v* row = (const uint4v*)(h1b + (size_t)r * 64);
    float acc[40];
#pragma unroll
    for (int c = 0; c < 40; ++c) acc[c] = 0.f;
    for (int c8 = 0; c8 < 16; ++c8) {   // 16 groups x 8 elems = full K=128
        uint4v u = row[c8];
        float aa[8];
#pragma unroll
        for (int j = 0; j < 4; ++j) {
            aa[2 * j]     = bflo(u[j]);
            aa[2 * j + 1] = bfhi(u[j]);
        }
        int kb = c8 * 8;
#pragma unroll
        for (int kk = 0; kk < 8; ++kk) {
            float av = aa[kk];
            const float4* wr = (const float4*)&w2s[(kb + kk) * 40];
#pragma unroll
            for (int c4 = 0; c4 < 10; ++c4) {
                float4 w = wr[c4];
                acc[c4 * 4 + 0] = fmaf(av, w.x, acc[c4 * 4 + 0]);
                acc[c4 * 4 + 1] = fmaf(av, w.y, acc[c4 * 4 + 1]);
                acc[c4 * 4 + 2] = fmaf(av, w.z, acc[c4 * 4 + 2]);
                acc[c4 * 4 + 3] = fmaf(av, w.w, acc[c4 * 4 + 3]);
            }
        }
    }
    float di = dinv[r];
    unsigned short* op = h2s + (size_t)r * 40;
#pragma unroll
    for (int c4 = 0; c4 < 10; ++c4) {
        ushort4v w;
        w[0] = f2bf(acc[c4 * 4 + 0] * di); w[1] = f2bf(acc[c4 * 4 + 1] * di);
        w[2] = f2bf(acc[c4 * 4 + 2] * di); w[3] = f2bf(acc[c4 * 4 + 3] * di);
        *(ushort4v*)(op + c4 * 4) = w;
    }
}

// ---------------------------------------------------------------------------
// Aggregation 2 + bias + log_softmax.  16x unrolled gathers.
// ---------------------------------------------------------------------------
__global__ __launch_bounds__(256) void k_agg2(const unsigned short* __restrict__ h2s,
                                              const float* __restrict__ dinv,
                                              const int* __restrict__ offsets,
                                              const int* __restrict__ esrc,
                                              const float* __restrict__ b2,
                                              float* __restrict__ out, int N) {
    int wid = (blockIdx.x * 256 + threadIdx.x) >> 6;
    if (wid >= N) return;
    int lane = threadIdx.x & 63;
    bool act = lane < 40;
    float acc = act ? bf1(h2s[(size_t)wid * 40 + lane]) : 0.f;  // self (prescaled)
    int beg = offsets[wid], end = offsets[wid + 1];
    for (int b0 = beg; b0 < end; b0 += 64) {
        int nb = min(64, end - b0);
        int idx = (lane < nb) ? esrc[b0 + lane] : 0;
        int k = 0;
        for (; k + 16 <= nb; k += 16) {
            float u[16];
#pragma unroll
            for (int j = 0; j < 16; ++j) {
                int s = __shfl(idx, k + j);
                u[j] = act ? bf1(h2s[(size_t)s * 40 + lane]) : 0.f;
            }
            float t0 = ((u[0] + u[1]) + (u[2] + u[3])) + ((u[4] + u[5]) + (u[6] + u[7]));
            float t1 = ((u[8] + u[9]) + (u[10] + u[11])) + ((u[12] + u[13]) + (u[14] + u[15]));
            acc += t0 + t1;
        }
        for (; k + 4 <= nb; k += 4) {
            int s0 = __shfl(idx, k + 0), s1 = __shfl(idx, k + 1);
            int s2 = __shfl(idx, k + 2), s3 = __shfl(idx, k + 3);
            float u0 = act ? bf1(h2s[(size_t)s0 * 40 + lane]) : 0.f;
            float u1 = act ? bf1(h2s[(size_t)s1 * 40 + lane]) : 0.f;
            float u2 = act ? bf1(h2s[(size_t)s2 * 40 + lane]) : 0.f;
            float u3 = act ? bf1(h2s[(size_t)s3 * 40 + lane]) : 0.f;
            acc += (u0 + u1) + (u2 + u3);
        }
        for (; k < nb; ++k) {
            int s = __shfl(idx, k);
            acc += act ? bf1(h2s[(size_t)s * 40 + lane]) : 0.f;
        }
    }
    float di = dinv[wid];
    float logit = fmaf(di, acc, act ? b2[lane] : 0.f);
    float m = act ? logit : -1e30f;
#pragma unroll
    for (int o = 32; o > 0; o >>= 1) m = fmaxf(m, __shfl_xor(m, o));
    float pv = act ? __expf(logit - m) : 0.f;
    float ssum = pv;
#pragma unroll
    for (int o = 32; o > 0; o >>= 1) ssum += __shfl_xor(ssum, o);
    if (act) out[(size_t)wid * 40 + lane] = logit - m - __logf(ssum);
}

extern "C" void kernel_launch(void* const* d_in, const int* in_sizes, int n_in,
                              void* d_out, int out_size, void* d_ws, size_t ws_size,
                              hipStream_t stream) {
    const float* x  = (const float*)d_in[0];
    const int*   ei = (const int*)d_in[1];
    const float* W1 = (const float*)d_in[2];
    const float* b1 = (const float*)d_in[3];
    const float* W2 = (const float*)d_in[4];
    const float* b2 = (const float*)d_in[5];
    float* out = (float*)d_out;

    int N = in_sizes[0] / 512;
    int E = in_sizes[1] / 2;
    const int* esrc_in = ei;
    const int* edst_in = ei + E;
    int nb = (N + 1023) / 1024;  // scan tiles

    char* p = (char*)d_ws;
    size_t off = 0;
    auto take = [&](size_t bytes) {
        size_t o = (off + 255) & ~(size_t)255;
        off = o + bytes;
        return (void*)(p + o);
    };
    unsigned short* h0s  = (unsigned short*)take((size_t)N * 128 * 2);  // bf16 prescaled
    unsigned*       h1b  = (unsigned*)take((size_t)N * 64 * 4);         // bf16x2 packed
    unsigned short* wswz = (unsigned short*)take((size_t)16 * 8 * 64 * 8 * 2);
    int*   deg  = (int*)take((size_t)N * 4);
    float* dinv = (float*)take((size_t)N * 4);
    int*   offs = (int*)take((size_t)(N + 1) * 4);
    int*   bsum = (int*)take((size_t)nb * 4);
    int*   bpre = (int*)take((size_t)nb * 4);
    int*   rank = (int*)take((size_t)E * 4);
    int*   esrc = (int*)take((size_t)E * 4);
    unsigned short* h2s = h0s;  // h0s dead after k_agg1

    hipMemsetAsync(deg, 0, (size_t)N * 4, stream);

    k_wswz<<<32, 256, 0, stream>>>(W1, wswz);
    k_deg <<<(E + 255) / 256, 256, 0, stream>>>(edst_in, deg, rank, E);
    k_bsum <<<nb, 256, 0, stream>>>(deg, bsum, N);
    k_scan2<<<1, 1024, 0, stream>>>(bsum, bpre, offs + N, nb);
    k_scan3<<<nb, 256, 0, stream>>>(deg, bpre, offs, dinv, N);
    k_fill<<<(E + 255) / 256, 256, 0, stream>>>(esrc_in, edst_in, offs, rank, esrc, E);

    k_gemm1<<<(N + 63) / 64, 256, 0, stream>>>(x, wswz, dinv, h0s, N);
    k_agg1 <<<(N + 3) / 4, 256, 0, stream>>>(h0s, dinv, offs, esrc, b1, h1b, N);
    k_gemm2<<<(N + 255) / 256, 256, 0, stream>>>(h1b, W2, dinv, h2s, N);
    k_agg2 <<<(N + 3) / 4, 256, 0, stream>>>(h2s, dinv, offs, esrc, b2, out, N);
}